// Round 8
// baseline (319.468 us; speedup 1.0000x reference)
//
#include <hip/hip_runtime.h>
#include <stdint.h>

#define NN 100000
#define NE 1600000
#define NBUCK 391            // ceil(NN/256)
#define CHUNK 16000          // big runs/bucket/chunk: single-XCD-owned scatter lines
#define NPART (NE / CHUNK)   // 100, exact

typedef __attribute__((ext_vector_type(8))) __bf16 bf16x8;
typedef __attribute__((ext_vector_type(4))) float  f32x4;
typedef unsigned int uint;

static __device__ __forceinline__ float blo(uint u) {
    union { uint i; float f; } v; v.i = u << 16; return v.f;
}
static __device__ __forceinline__ float bhi(uint u) {
    union { uint i; float f; } v; v.i = u & 0xffff0000u; return v.f;
}
static __device__ __forceinline__ uint packbf(float a, float b) {
    union { __bf16 h[2]; uint u; } v;
    v.h[0] = (__bf16)a; v.h[1] = (__bf16)b;
    return v.u;
}

// Preformatted W in the exact LDS fragment layout (hi/lo bf16 split).
__device__ __align__(16) __bf16 g_w1hi[16384];
__device__ __align__(16) __bf16 g_w1lo[16384];
__device__ __align__(16) __bf16 g_w2hi[8192];
__device__ __align__(16) __bf16 g_w2lo[8192];

// ---------- A: per-chunk histogram (blocks 0..NPART-1) + prep_w (block NPART) ----------
// Writes cnt_d[b*NBUCK+t], cnt_s[b*NBUCK+t] — no global atomics, fully coalesced.
__global__ __launch_bounds__(1024) void hist_prep(const int* __restrict__ src,
        const int* __restrict__ dst, int* __restrict__ cnt_d, int* __restrict__ cnt_s,
        const float* __restrict__ W1, const float* __restrict__ W2)
{
    if (blockIdx.x == NPART) {
        // prep_w: 3072 fragment jobs on 1024 threads
        #pragma unroll
        for (int k = 0; k < 3; ++k) {
            int gid = threadIdx.x + k * 1024;
            const float* W; __bf16* hi; __bf16* lo; int F; int idx;
            if (gid < 2048)      { W = W1; hi = g_w1hi; lo = g_w1lo; F = 128; idx = gid; }
            else                 { W = W2; hi = g_w2hi; lo = g_w2lo; F = 64;  idx = gid - 2048; }
            int cb = idx >> 8;
            int kc = (idx >> 6) & 3;
            int ln = idx & 63;
            int col = cb*16 + (ln & 15);
            int kb  = kc*32 + (ln >> 4)*8;
            bf16x8 vh, vl;
            #pragma unroll
            for (int j = 0; j < 8; ++j) {
                float f = W[(size_t)(kb + j)*F + col];
                __bf16 h = (__bf16)f;
                vh[j] = h;
                vl[j] = (__bf16)(f - (float)h);
            }
            *(bf16x8*)(hi + idx*8) = vh;
            *(bf16x8*)(lo + idx*8) = vl;
        }
        return;
    }
    __shared__ int hd[4][NBUCK], hs[4][NBUCK];
    int beg = blockIdx.x * CHUNK;
    int end = beg + CHUNK;
    for (int t = threadIdx.x; t < NBUCK; t += 1024) {
        hd[0][t] = 0; hd[1][t] = 0; hd[2][t] = 0; hd[3][t] = 0;
        hs[0][t] = 0; hs[1][t] = 0; hs[2][t] = 0; hs[3][t] = 0;
    }
    __syncthreads();
    const int c = (threadIdx.x >> 6) & 3;
    for (int i = beg + threadIdx.x * 4; i + 4 <= end; i += 4096) {
        int4 d = *(const int4*)(dst + i);
        int4 s = *(const int4*)(src + i);
        atomicAdd(&hd[c][d.x >> 8], 1); atomicAdd(&hd[c][d.y >> 8], 1);
        atomicAdd(&hd[c][d.z >> 8], 1); atomicAdd(&hd[c][d.w >> 8], 1);
        atomicAdd(&hs[c][s.x >> 8], 1); atomicAdd(&hs[c][s.y >> 8], 1);
        atomicAdd(&hs[c][s.z >> 8], 1); atomicAdd(&hs[c][s.w >> 8], 1);
    }
    __syncthreads();
    int* cd = cnt_d + blockIdx.x * NBUCK;
    int* cs = cnt_s + blockIdx.x * NBUCK;
    for (int t = threadIdx.x; t < NBUCK; t += 1024) {
        cd[t] = hd[0][t] + hd[1][t] + hd[2][t] + hd[3][t];
        cs[t] = hs[0][t] + hs[1][t] + hs[2][t] + hs[3][t];
    }
}

// ---------- B: scan totals + per-chunk base matrices (deterministic allocation) ----------
__global__ __launch_bounds__(512) void scan_bases(const int* __restrict__ cnt_d,
        const int* __restrict__ cnt_s, int* __restrict__ base_d, int* __restrict__ base_s,
        int* __restrict__ offd, int* __restrict__ offs, int* __restrict__ row_ptr,
        int n, int e)
{
    __shared__ int sh[512];
    int t = threadIdx.x;
    // ---- dst ----
    int run = 0;
    if (t < NBUCK) {
        for (int b = 0; b < NPART; ++b) {
            int idx = b * NBUCK + t;
            base_d[idx] = run;
            run += cnt_d[idx];
        }
    }
    sh[t] = (t < NBUCK) ? run : 0;
    __syncthreads();
    int v = sh[t];
    for (int o = 1; o < 512; o <<= 1) {
        int tv = (t >= o) ? sh[t - o] : 0;
        __syncthreads();
        sh[t] += tv;
        __syncthreads();
    }
    int ex = sh[t] - v;
    if (t < NBUCK) {
        offd[t] = ex;
        for (int b = 0; b < NPART; ++b) base_d[b * NBUCK + t] += ex;
    }
    if (t == 0) { offd[NBUCK] = e; row_ptr[n] = e; }
    __syncthreads();
    // ---- src ----
    run = 0;
    if (t < NBUCK) {
        for (int b = 0; b < NPART; ++b) {
            int idx = b * NBUCK + t;
            base_s[idx] = run;
            run += cnt_s[idx];
        }
    }
    sh[t] = (t < NBUCK) ? run : 0;
    __syncthreads();
    v = sh[t];
    for (int o = 1; o < 512; o <<= 1) {
        int tv = (t >= o) ? sh[t - o] : 0;
        __syncthreads();
        sh[t] += tv;
        __syncthreads();
    }
    ex = sh[t] - v;
    if (t < NBUCK) {
        offs[t] = ex;
        for (int b = 0; b < NPART; ++b) base_s[b * NBUCK + t] += ex;
    }
    if (t == 0) offs[NBUCK] = e;
}

// ---------- C: scatter with precomputed bases (LDS atomics only) ----------
__global__ __launch_bounds__(1024) void scatter(const int* __restrict__ src,
        const int* __restrict__ dst, const int* __restrict__ base_d,
        const int* __restrict__ base_s, uint* __restrict__ pairs,
        int* __restrict__ bsrc, int e)
{
    __shared__ int based[NBUCK], bases[NBUCK];
    int b = blockIdx.x;
    int beg = b * CHUNK;
    int end = beg + CHUNK;
    for (int t = threadIdx.x; t < NBUCK; t += 1024) {
        based[t] = base_d[b * NBUCK + t];
        bases[t] = base_s[b * NBUCK + t];
    }
    __syncthreads();
    for (int i = beg + threadIdx.x; i < end; i += 1024) {
        int s = src[i], d = dst[i];
        int pd = atomicAdd(&based[d >> 8], 1);     // LDS atomic
        pairs[pd] = ((uint)(d & 255) << 24) | (uint)s;
        int ps = atomicAdd(&bases[s >> 8], 1);     // LDS atomic
        bsrc[ps] = s;
    }
}

// ---------- fine: one block per bucket (dst: row_ptr/nd/CSR; src: ns) ----------
__global__ __launch_bounds__(256) void fine_both(const int* __restrict__ offd,
        const uint* __restrict__ pairs, const int* __restrict__ offs,
        const int* __restrict__ bsrc, int* __restrict__ row_ptr,
        float* __restrict__ nd, float* __restrict__ ns, int* __restrict__ csr, int n)
{
    __shared__ int h[256], sh[256], cur[256];
    int b = blockIdx.x;
    int t = threadIdx.x;
    int node = (b << 8) + t;
    // ---- dst phase ----
    int beg = offd[b], end = offd[b + 1];
    h[t] = 0;
    __syncthreads();
    for (int i = beg + t; i < end; i += 256)
        atomicAdd(&h[pairs[i] >> 24], 1);
    __syncthreads();
    int v = h[t];
    sh[t] = v;
    __syncthreads();
    for (int o = 1; o < 256; o <<= 1) {
        int tv = (t >= o) ? sh[t - o] : 0;
        __syncthreads();
        sh[t] += tv;
        __syncthreads();
    }
    int ex = sh[t] - v;
    if (node < n) {
        row_ptr[node] = beg + ex;
        nd[node] = rsqrtf((float)v + 1.0f);        // +1 self-loop
    }
    cur[t] = beg + ex;
    __syncthreads();
    for (int i = beg + t; i < end; i += 256) {
        uint pr = pairs[i];
        int pos = atomicAdd(&cur[pr >> 24], 1);    // LDS atomic
        csr[pos] = (int)(pr & 0x00FFFFFFu);
    }
    // ---- src phase ----
    h[t] = 0;
    __syncthreads();
    int sbeg = offs[b], send = offs[b + 1];
    for (int i = sbeg + t; i < send; i += 256)
        atomicAdd(&h[bsrc[i] & 255], 1);
    __syncthreads();
    if (node < n) ns[node] = rsqrtf((float)h[t] + 1.0f);
}

// ---------- layer-1 MFMA GEMM, f32 A via split-bf16, LDS-staged W ----------
template<int F, bool SCALE>
__global__ __launch_bounds__(256) void gemm_mfma(const float* __restrict__ X,
        const float* __restrict__ rowscale, __bf16* __restrict__ xw, int nchunks)
{
    __shared__ __bf16 Whi[(F/16)*4*64*8];
    __shared__ __bf16 Wlo[(F/16)*4*64*8];
    {
        const uint4* gh = (const uint4*)((F == 128) ? g_w1hi : g_w2hi);
        const uint4* gl = (const uint4*)((F == 128) ? g_w1lo : g_w2lo);
        uint4* lh = (uint4*)Whi;
        uint4* ll = (uint4*)Wlo;
        constexpr int NU4 = 16 * F;
        for (int i = threadIdx.x; i < NU4; i += 256) {
            lh[i] = gh[i];
            ll[i] = gl[i];
        }
    }
    __syncthreads();
    const int lane = threadIdx.x & 63;
    const int m = lane & 15, q = lane >> 4;
    int c = blockIdx.x*4 + (threadIdx.x >> 6);
    if (c >= nchunks) return;
    int rbase = c*16;
    const float* xrow = X + (size_t)(rbase + m)*128;
    f32x4 acc[F/16];
    #pragma unroll
    for (int i = 0; i < F/16; ++i) acc[i] = (f32x4)0.f;
    #pragma unroll
    for (int kc = 0; kc < 4; ++kc) {
        int kb = kc*32 + q*8;
        float4 v0 = *(const float4*)(xrow + kb);
        float4 v1 = *(const float4*)(xrow + kb + 4);
        float xf[8] = {v0.x, v0.y, v0.z, v0.w, v1.x, v1.y, v1.z, v1.w};
        bf16x8 ahi, alo;
        #pragma unroll
        for (int j = 0; j < 8; ++j) {
            __bf16 h = (__bf16)xf[j];
            ahi[j] = h;
            alo[j] = (__bf16)(xf[j] - (float)h);
        }
        #pragma unroll
        for (int cb = 0; cb < F/16; ++cb) {
            bf16x8 bh = *(const bf16x8*)(Whi + ((cb*4 + kc)*64 + lane)*8);
            bf16x8 bl = *(const bf16x8*)(Wlo + ((cb*4 + kc)*64 + lane)*8);
            acc[cb] = __builtin_amdgcn_mfma_f32_16x16x32_bf16(ahi, bh, acc[cb], 0, 0, 0);
            acc[cb] = __builtin_amdgcn_mfma_f32_16x16x32_bf16(alo, bh, acc[cb], 0, 0, 0);
            acc[cb] = __builtin_amdgcn_mfma_f32_16x16x32_bf16(ahi, bl, acc[cb], 0, 0, 0);
        }
    }
    float s[4];
    #pragma unroll
    for (int reg = 0; reg < 4; ++reg)
        s[reg] = SCALE ? rowscale[rbase + q*4 + reg] : 1.0f;
    #pragma unroll
    for (int cb = 0; cb < F/16; ++cb)
        #pragma unroll
        for (int reg = 0; reg < 4; ++reg)
            xw[(size_t)(rbase + q*4 + reg)*F + cb*16 + m] = (__bf16)(acc[cb][reg] * s[reg]);
}

// ---------- layer-2 MFMA GEMM, bf16 A direct, LDS-staged W ----------
template<int F>
__global__ __launch_bounds__(256) void gemm_mfma_bf16(const __bf16* __restrict__ X,
        __bf16* __restrict__ xw, int nchunks)
{
    __shared__ __bf16 Whi[(F/16)*4*64*8];
    __shared__ __bf16 Wlo[(F/16)*4*64*8];
    {
        const uint4* gh = (const uint4*)((F == 128) ? g_w1hi : g_w2hi);
        const uint4* gl = (const uint4*)((F == 128) ? g_w1lo : g_w2lo);
        uint4* lh = (uint4*)Whi;
        uint4* ll = (uint4*)Wlo;
        constexpr int NU4 = 16 * F;
        for (int i = threadIdx.x; i < NU4; i += 256) {
            lh[i] = gh[i];
            ll[i] = gl[i];
        }
    }
    __syncthreads();
    const int lane = threadIdx.x & 63;
    const int m = lane & 15, q = lane >> 4;
    int c = blockIdx.x*4 + (threadIdx.x >> 6);
    if (c >= nchunks) return;
    int rbase = c*16;
    const __bf16* xrow = X + (size_t)(rbase + m)*128;
    f32x4 acc[F/16];
    #pragma unroll
    for (int i = 0; i < F/16; ++i) acc[i] = (f32x4)0.f;
    #pragma unroll
    for (int kc = 0; kc < 4; ++kc) {
        int kb = kc*32 + q*8;
        bf16x8 a = *(const bf16x8*)(xrow + kb);
        #pragma unroll
        for (int cb = 0; cb < F/16; ++cb) {
            bf16x8 bh = *(const bf16x8*)(Whi + ((cb*4 + kc)*64 + lane)*8);
            bf16x8 bl = *(const bf16x8*)(Wlo + ((cb*4 + kc)*64 + lane)*8);
            acc[cb] = __builtin_amdgcn_mfma_f32_16x16x32_bf16(a, bh, acc[cb], 0, 0, 0);
            acc[cb] = __builtin_amdgcn_mfma_f32_16x16x32_bf16(a, bl, acc[cb], 0, 0, 0);
        }
    }
    #pragma unroll
    for (int cb = 0; cb < F/16; ++cb)
        #pragma unroll
        for (int reg = 0; reg < 4; ++reg)
            xw[(size_t)(rbase + q*4 + reg)*F + cb*16 + m] = (__bf16)acc[cb][reg];
}

// ---------- layer-1 aggregate: quarter-wave per node ----------
__global__ __launch_bounds__(256) void agg_csr128(const int* __restrict__ row_ptr,
        const int* __restrict__ csr, const uint4* __restrict__ xw,
        const float* __restrict__ nd, const float* __restrict__ ns,
        const float* __restrict__ b, __bf16* __restrict__ out, int n)
{
    int r = blockIdx.x * 16 + (threadIdx.x >> 4);
    if (r >= n) return;
    const int ql = threadIdx.x & 15;
    int beg = row_ptr[r], end = row_ptr[r + 1];
    float a[8];
    {
        uint4 u = xw[(size_t)r * 16 + ql];          // self-loop
        a[0]=blo(u.x); a[1]=bhi(u.x); a[2]=blo(u.y); a[3]=bhi(u.y);
        a[4]=blo(u.z); a[5]=bhi(u.z); a[6]=blo(u.w); a[7]=bhi(u.w);
    }
    int j = beg;
    for (; j + 4 <= end; j += 4) {                  // 4 gathers in flight per lane
        int s0 = csr[j], s1 = csr[j+1], s2 = csr[j+2], s3 = csr[j+3];
        uint4 u0 = xw[(size_t)s0 * 16 + ql];
        uint4 u1 = xw[(size_t)s1 * 16 + ql];
        uint4 u2 = xw[(size_t)s2 * 16 + ql];
        uint4 u3 = xw[(size_t)s3 * 16 + ql];
        a[0]+=blo(u0.x)+blo(u1.x)+blo(u2.x)+blo(u3.x); a[1]+=bhi(u0.x)+bhi(u1.x)+bhi(u2.x)+bhi(u3.x);
        a[2]+=blo(u0.y)+blo(u1.y)+blo(u2.y)+blo(u3.y); a[3]+=bhi(u0.y)+bhi(u1.y)+bhi(u2.y)+bhi(u3.y);
        a[4]+=blo(u0.z)+blo(u1.z)+blo(u2.z)+blo(u3.z); a[5]+=bhi(u0.z)+bhi(u1.z)+bhi(u2.z)+bhi(u3.z);
        a[6]+=blo(u0.w)+blo(u1.w)+blo(u2.w)+blo(u3.w); a[7]+=bhi(u0.w)+bhi(u1.w)+bhi(u2.w)+bhi(u3.w);
    }
    for (; j < end; ++j) {
        uint4 u0 = xw[(size_t)csr[j] * 16 + ql];
        a[0]+=blo(u0.x); a[1]+=bhi(u0.x); a[2]+=blo(u0.y); a[3]+=bhi(u0.y);
        a[4]+=blo(u0.z); a[5]+=bhi(u0.z); a[6]+=blo(u0.w); a[7]+=bhi(u0.w);
    }
    float ndr = nd[r], nsr = ns[r];
    float4 b0 = *(const float4*)(b + ql * 8);
    float4 b1 = *(const float4*)(b + ql * 8 + 4);
    uint4 pk;
    pk.x = packbf(fmaxf(a[0]*ndr + b0.x, 0.f) * nsr, fmaxf(a[1]*ndr + b0.y, 0.f) * nsr);
    pk.y = packbf(fmaxf(a[2]*ndr + b0.z, 0.f) * nsr, fmaxf(a[3]*ndr + b0.w, 0.f) * nsr);
    pk.z = packbf(fmaxf(a[4]*ndr + b1.x, 0.f) * nsr, fmaxf(a[5]*ndr + b1.y, 0.f) * nsr);
    pk.w = packbf(fmaxf(a[6]*ndr + b1.z, 0.f) * nsr, fmaxf(a[7]*ndr + b1.w, 0.f) * nsr);
    ((uint4*)(out + (size_t)r * 128))[ql] = pk;
}

// ---------- layer-2 aggregate: eighth-wave (8 lanes) per node, uint4 lanes ----------
__global__ __launch_bounds__(256) void agg_csr64(const int* __restrict__ row_ptr,
        const int* __restrict__ csr, const uint4* __restrict__ xw,
        const float* __restrict__ nd, const float* __restrict__ b,
        float* __restrict__ out, int n)
{
    int r = blockIdx.x * 32 + (threadIdx.x >> 3);
    if (r >= n) return;
    const int ql = threadIdx.x & 7;
    int beg = row_ptr[r], end = row_ptr[r + 1];
    float a[8];
    {
        uint4 u = xw[(size_t)r * 8 + ql];           // self-loop
        a[0]=blo(u.x); a[1]=bhi(u.x); a[2]=blo(u.y); a[3]=bhi(u.y);
        a[4]=blo(u.z); a[5]=bhi(u.z); a[6]=blo(u.w); a[7]=bhi(u.w);
    }
    int j = beg;
    for (; j + 4 <= end; j += 4) {
        int s0 = csr[j], s1 = csr[j+1], s2 = csr[j+2], s3 = csr[j+3];
        uint4 u0 = xw[(size_t)s0 * 8 + ql];
        uint4 u1 = xw[(size_t)s1 * 8 + ql];
        uint4 u2 = xw[(size_t)s2 * 8 + ql];
        uint4 u3 = xw[(size_t)s3 * 8 + ql];
        a[0]+=blo(u0.x)+blo(u1.x)+blo(u2.x)+blo(u3.x); a[1]+=bhi(u0.x)+bhi(u1.x)+bhi(u2.x)+bhi(u3.x);
        a[2]+=blo(u0.y)+blo(u1.y)+blo(u2.y)+blo(u3.y); a[3]+=bhi(u0.y)+bhi(u1.y)+bhi(u2.y)+bhi(u3.y);
        a[4]+=blo(u0.z)+blo(u1.z)+blo(u2.z)+blo(u3.z); a[5]+=bhi(u0.z)+bhi(u1.z)+bhi(u2.z)+bhi(u3.z);
        a[6]+=blo(u0.w)+blo(u1.w)+blo(u2.w)+blo(u3.w); a[7]+=bhi(u0.w)+bhi(u1.w)+bhi(u2.w)+bhi(u3.w);
    }
    for (; j < end; ++j) {
        uint4 u0 = xw[(size_t)csr[j] * 8 + ql];
        a[0]+=blo(u0.x); a[1]+=bhi(u0.x); a[2]+=blo(u0.y); a[3]+=bhi(u0.y);
        a[4]+=blo(u0.z); a[5]+=bhi(u0.z); a[6]+=blo(u0.w); a[7]+=bhi(u0.w);
    }
    float ndr = nd[r];
    float4 b0 = *(const float4*)(b + ql * 8);
    float4 b1 = *(const float4*)(b + ql * 8 + 4);
    float4 o0, o1;
    o0.x = a[0]*ndr + b0.x;
    o0.y = a[1]*ndr + b0.y;
    o0.z = a[2]*ndr + b0.z;
    o0.w = a[3]*ndr + b0.w;
    o1.x = a[4]*ndr + b1.x;
    o1.y = a[5]*ndr + b1.y;
    o1.z = a[6]*ndr + b1.z;
    o1.w = a[7]*ndr + b1.w;
    float* op = out + (size_t)r * 64 + ql * 8;
    *(float4*)op = o0;
    *(float4*)(op + 4) = o1;
}

extern "C" void kernel_launch(void* const* d_in, const int* in_sizes, int n_in,
                              void* d_out, int out_size, void* d_ws, size_t ws_size,
                              hipStream_t stream)
{
    const float* x  = (const float*)d_in[0];   // [N,128] f32
    const int* src  = (const int*)d_in[1];     // [E]
    const int* dst  = (const int*)d_in[2];     // [E]
    const float* W1 = (const float*)d_in[3];   // [128,128] f32
    const float* b1 = (const float*)d_in[4];   // [128] f32
    const float* W2 = (const float*)d_in[5];   // [128,64] f32
    const float* b2 = (const float*)d_in[6];   // [64] f32
    float* out = (float*)d_out;                // [N,64] f32

    const int n = NN, e = NE;
    const int nchunks = n / 16;                // 6250, exact
    const int gemm_grid = (nchunks + 3) / 4;   // 1563

    // workspace layout
    char* p = (char*)d_ws;
    float* ns      = (float*)p; p += (size_t)n * 4;
    float* nd      = (float*)p; p += (size_t)n * 4;
    int*   row_ptr = (int*)p;   p += (size_t)(n + 1) * 4;
    int*   offd    = (int*)p;   p += (size_t)(NBUCK + 1) * 4;
    int*   offs    = (int*)p;   p += (size_t)(NBUCK + 1) * 4;
    int*   cnt_d   = (int*)p;   p += (size_t)NPART * NBUCK * 4;
    int*   cnt_s   = (int*)p;   p += (size_t)NPART * NBUCK * 4;
    int*   base_d  = (int*)p;   p += (size_t)NPART * NBUCK * 4;
    int*   base_s  = (int*)p;   p += (size_t)NPART * NBUCK * 4;
    int*   csr     = (int*)p;   p += (size_t)e * 4;
    p = (char*)(((uintptr_t)p + 255) & ~(uintptr_t)255);
    __bf16* bufA   = (__bf16*)p; p += (size_t)128 * n * 2;  // xw1 bf16, then xw2 bf16
    p = (char*)(((uintptr_t)p + 255) & ~(uintptr_t)255);
    __bf16* bufB   = (__bf16*)p;                             // h bf16 [N,128]
    uint*  pairs   = (uint*)bufB;                            // build-phase only
    int*   bsrc    = (int*)bufA;                             // build-phase only

    hist_prep<<<NPART + 1, 1024, 0, stream>>>(src, dst, cnt_d, cnt_s, W1, W2);
    scan_bases<<<1, 512, 0, stream>>>(cnt_d, cnt_s, base_d, base_s, offd, offs, row_ptr, n, e);
    scatter<<<NPART, 1024, 0, stream>>>(src, dst, base_d, base_s, pairs, bsrc, e);
    fine_both<<<NBUCK, 256, 0, stream>>>(offd, pairs, offs, bsrc, row_ptr, nd, ns, csr, n);

    // layer 1: xw1 = bf16((x @ W1) * ns) ; h = bf16(relu((xw1[r]+sum nbr)*nd + b1) * ns)
    gemm_mfma<128, true><<<gemm_grid, 256, 0, stream>>>(x, ns, bufA, nchunks);
    agg_csr128<<<(n + 15) / 16, 256, 0, stream>>>(row_ptr, csr, (const uint4*)bufA, nd, ns, b1, bufB, n);

    // layer 2: xw2 = bf16(h @ W2) ; out = (xw2[r]+sum nbr)*nd + b2
    gemm_mfma_bf16<64><<<gemm_grid, 256, 0, stream>>>(bufB, bufA, nchunks);
    agg_csr64<<<(n + 31) / 32, 256, 0, stream>>>(row_ptr, csr, (const uint4*)bufA, nd, b2, out, n);
}

// Round 9
// 298.405 us; speedup vs baseline: 1.0706x; 1.0706x over previous
//
#include <hip/hip_runtime.h>
#include <stdint.h>

#define NN 100000
#define NE 1600000
#define NBUCK 391            // ceil(NN/256)
#define CHUNK 16000          // big runs/bucket/chunk: single-XCD-owned scatter lines
#define NPART (NE / CHUNK)   // 100, exact

typedef __attribute__((ext_vector_type(8))) __bf16 bf16x8;
typedef __attribute__((ext_vector_type(4))) float  f32x4;
typedef unsigned int uint;

static __device__ __forceinline__ float blo(uint u) {
    union { uint i; float f; } v; v.i = u << 16; return v.f;
}
static __device__ __forceinline__ float bhi(uint u) {
    union { uint i; float f; } v; v.i = u & 0xffff0000u; return v.f;
}
static __device__ __forceinline__ uint packbf(float a, float b) {
    union { __bf16 h[2]; uint u; } v;
    v.h[0] = (__bf16)a; v.h[1] = (__bf16)b;
    return v.u;
}

// Preformatted W in the exact LDS fragment layout (hi/lo bf16 split).
__device__ __align__(16) __bf16 g_w1hi[16384];
__device__ __align__(16) __bf16 g_w1lo[16384];
__device__ __align__(16) __bf16 g_w2hi[8192];
__device__ __align__(16) __bf16 g_w2lo[8192];

// ---------- prep_w fused with counter zeroing ----------
__global__ __launch_bounds__(256) void prep_w(const float* __restrict__ W1,
        const float* __restrict__ W2, int* __restrict__ cdcs)
{
    int gid = blockIdx.x * 256 + threadIdx.x;
    if (gid >= 3072) {
        int z = gid - 3072;
        if (z < 2 * NBUCK) cdcs[z] = 0;
        return;
    }
    const float* W; __bf16* hi; __bf16* lo; int F; int idx;
    if (gid < 2048)      { W = W1; hi = g_w1hi; lo = g_w1lo; F = 128; idx = gid; }
    else                 { W = W2; hi = g_w2hi; lo = g_w2lo; F = 64;  idx = gid - 2048; }
    int cb = idx >> 8;
    int kc = (idx >> 6) & 3;
    int ln = idx & 63;
    int col = cb*16 + (ln & 15);
    int kb  = kc*32 + (ln >> 4)*8;
    bf16x8 vh, vl;
    #pragma unroll
    for (int j = 0; j < 8; ++j) {
        float f = W[(size_t)(kb + j)*F + col];
        __bf16 h = (__bf16)f;
        vh[j] = h;
        vl[j] = (__bf16)(f - (float)h);
    }
    *(bf16x8*)(hi + idx*8) = vh;
    *(bf16x8*)(lo + idx*8) = vl;
}

__global__ __launch_bounds__(256) void coarse_hist(const int4* __restrict__ src4,
        const int4* __restrict__ dst4, int* __restrict__ cd, int* __restrict__ cs, int e4)
{
    __shared__ int hd[2][NBUCK], hs[2][NBUCK];
    for (int t = threadIdx.x; t < NBUCK; t += 256) {
        hd[0][t] = 0; hd[1][t] = 0; hs[0][t] = 0; hs[1][t] = 0;
    }
    __syncthreads();
    const int c = (threadIdx.x >> 6) & 1;
    for (int i = blockIdx.x * 256 + threadIdx.x; i < e4; i += gridDim.x * 256) {
        int4 d = dst4[i], s = src4[i];
        atomicAdd(&hd[c][d.x >> 8], 1); atomicAdd(&hd[c][d.y >> 8], 1);
        atomicAdd(&hd[c][d.z >> 8], 1); atomicAdd(&hd[c][d.w >> 8], 1);
        atomicAdd(&hs[c][s.x >> 8], 1); atomicAdd(&hs[c][s.y >> 8], 1);
        atomicAdd(&hs[c][s.z >> 8], 1); atomicAdd(&hs[c][s.w >> 8], 1);
    }
    __syncthreads();
    for (int t = threadIdx.x; t < NBUCK; t += 256) {
        int vd = hd[0][t] + hd[1][t];
        int vs = hs[0][t] + hs[1][t];
        if (vd) atomicAdd(&cd[t], vd);
        if (vs) atomicAdd(&cs[t], vs);
    }
}

__global__ __launch_bounds__(512) void scan_coarse(const int* __restrict__ cd,
        const int* __restrict__ cs, int* __restrict__ offd, int* __restrict__ offs,
        int* __restrict__ curd, int* __restrict__ curs, int* __restrict__ row_ptr,
        int n, int e)
{
    __shared__ int sh[512];
    int t = threadIdx.x;
    int v = (t < NBUCK) ? cd[t] : 0;
    sh[t] = v;
    __syncthreads();
    for (int o = 1; o < 512; o <<= 1) {
        int tv = (t >= o) ? sh[t - o] : 0;
        __syncthreads();
        sh[t] += tv;
        __syncthreads();
    }
    if (t < NBUCK) { int ex = sh[t] - v; offd[t] = ex; curd[t] = ex; }
    if (t == 0) { offd[NBUCK] = e; row_ptr[n] = e; }
    __syncthreads();
    v = (t < NBUCK) ? cs[t] : 0;
    sh[t] = v;
    __syncthreads();
    for (int o = 1; o < 512; o <<= 1) {
        int tv = (t >= o) ? sh[t - o] : 0;
        __syncthreads();
        sh[t] += tv;
        __syncthreads();
    }
    if (t < NBUCK) { int ex = sh[t] - v; offs[t] = ex; curs[t] = ex; }
    if (t == 0) offs[NBUCK] = e;
}

// partition edges by dst>>8 (packed 4B pairs) AND src values by src>>8 (bsrc).
// CHUNK=16000, block=1024: per-bucket runs ~160B so pairs/bsrc lines are
// single-XCD-owned (write amp ~5.5x -> ~1.4x). 4-way hist copies cut LDS
// atomic serialization in the counting phase.
__global__ __launch_bounds__(1024) void part_both(const int* __restrict__ src,
        const int* __restrict__ dst, int* __restrict__ curd, int* __restrict__ curs,
        uint* __restrict__ pairs, int* __restrict__ bsrc, int e)
{
    __shared__ int hd[4][NBUCK], hs[4][NBUCK];
    __shared__ int based[NBUCK], bases[NBUCK];
    int beg = blockIdx.x * CHUNK;
    int end = beg + CHUNK; if (end > e) end = e;
    for (int t = threadIdx.x; t < NBUCK; t += 1024) {
        hd[0][t] = 0; hd[1][t] = 0; hd[2][t] = 0; hd[3][t] = 0;
        hs[0][t] = 0; hs[1][t] = 0; hs[2][t] = 0; hs[3][t] = 0;
    }
    __syncthreads();
    const int c = (threadIdx.x >> 6) & 3;
    for (int i = beg + threadIdx.x * 4; i + 4 <= end; i += 4096) {
        int4 d = *(const int4*)(dst + i);
        int4 s = *(const int4*)(src + i);
        atomicAdd(&hd[c][d.x >> 8], 1); atomicAdd(&hd[c][d.y >> 8], 1);
        atomicAdd(&hd[c][d.z >> 8], 1); atomicAdd(&hd[c][d.w >> 8], 1);
        atomicAdd(&hs[c][s.x >> 8], 1); atomicAdd(&hs[c][s.y >> 8], 1);
        atomicAdd(&hs[c][s.z >> 8], 1); atomicAdd(&hs[c][s.w >> 8], 1);
    }
    __syncthreads();
    for (int t = threadIdx.x; t < NBUCK; t += 1024) {
        int vd = hd[0][t] + hd[1][t] + hd[2][t] + hd[3][t];
        int vs = hs[0][t] + hs[1][t] + hs[2][t] + hs[3][t];
        based[t] = vd ? atomicAdd(&curd[t], vd) : 0;
        bases[t] = vs ? atomicAdd(&curs[t], vs) : 0;
    }
    __syncthreads();
    for (int i = beg + threadIdx.x; i < end; i += 1024) {
        int s = src[i], d = dst[i];
        int pd = atomicAdd(&based[d >> 8], 1);     // LDS atomic
        pairs[pd] = ((uint)(d & 255) << 24) | (uint)s;
        int ps = atomicAdd(&bases[s >> 8], 1);     // LDS atomic
        bsrc[ps] = s;
    }
}

__global__ __launch_bounds__(256) void fine_both(const int* __restrict__ offd,
        const uint* __restrict__ pairs, const int* __restrict__ offs,
        const int* __restrict__ bsrc, int* __restrict__ row_ptr,
        float* __restrict__ nd, float* __restrict__ ns, int* __restrict__ csr, int n)
{
    __shared__ int h[256], sh[256], cur[256];
    int b = blockIdx.x;
    int t = threadIdx.x;
    int node = (b << 8) + t;
    // ---- dst phase ----
    int beg = offd[b], end = offd[b + 1];
    h[t] = 0;
    __syncthreads();
    for (int i = beg + t; i < end; i += 256)
        atomicAdd(&h[pairs[i] >> 24], 1);
    __syncthreads();
    int v = h[t];
    sh[t] = v;
    __syncthreads();
    for (int o = 1; o < 256; o <<= 1) {
        int tv = (t >= o) ? sh[t - o] : 0;
        __syncthreads();
        sh[t] += tv;
        __syncthreads();
    }
    int ex = sh[t] - v;
    if (node < n) {
        row_ptr[node] = beg + ex;
        nd[node] = rsqrtf((float)v + 1.0f);        // +1 self-loop
    }
    cur[t] = beg + ex;
    __syncthreads();
    for (int i = beg + t; i < end; i += 256) {
        uint pr = pairs[i];
        int pos = atomicAdd(&cur[pr >> 24], 1);    // LDS atomic
        csr[pos] = (int)(pr & 0x00FFFFFFu);
    }
    // ---- src phase ----
    h[t] = 0;
    __syncthreads();
    int sbeg = offs[b], send = offs[b + 1];
    for (int i = sbeg + t; i < send; i += 256)
        atomicAdd(&h[bsrc[i] & 255], 1);
    __syncthreads();
    if (node < n) ns[node] = rsqrtf((float)h[t] + 1.0f);
}

// ---------- layer-1 MFMA GEMM, f32 A via split-bf16, LDS-staged W ----------
template<int F, bool SCALE>
__global__ __launch_bounds__(256) void gemm_mfma(const float* __restrict__ X,
        const float* __restrict__ rowscale, __bf16* __restrict__ xw, int nchunks)
{
    __shared__ __bf16 Whi[(F/16)*4*64*8];
    __shared__ __bf16 Wlo[(F/16)*4*64*8];
    {
        const uint4* gh = (const uint4*)((F == 128) ? g_w1hi : g_w2hi);
        const uint4* gl = (const uint4*)((F == 128) ? g_w1lo : g_w2lo);
        uint4* lh = (uint4*)Whi;
        uint4* ll = (uint4*)Wlo;
        constexpr int NU4 = 16 * F;
        for (int i = threadIdx.x; i < NU4; i += 256) {
            lh[i] = gh[i];
            ll[i] = gl[i];
        }
    }
    __syncthreads();
    const int lane = threadIdx.x & 63;
    const int m = lane & 15, q = lane >> 4;
    int c = blockIdx.x*4 + (threadIdx.x >> 6);
    if (c >= nchunks) return;
    int rbase = c*16;
    const float* xrow = X + (size_t)(rbase + m)*128;
    f32x4 acc[F/16];
    #pragma unroll
    for (int i = 0; i < F/16; ++i) acc[i] = (f32x4)0.f;
    #pragma unroll
    for (int kc = 0; kc < 4; ++kc) {
        int kb = kc*32 + q*8;
        float4 v0 = *(const float4*)(xrow + kb);
        float4 v1 = *(const float4*)(xrow + kb + 4);
        float xf[8] = {v0.x, v0.y, v0.z, v0.w, v1.x, v1.y, v1.z, v1.w};
        bf16x8 ahi, alo;
        #pragma unroll
        for (int j = 0; j < 8; ++j) {
            __bf16 h = (__bf16)xf[j];
            ahi[j] = h;
            alo[j] = (__bf16)(xf[j] - (float)h);
        }
        #pragma unroll
        for (int cb = 0; cb < F/16; ++cb) {
            bf16x8 bh = *(const bf16x8*)(Whi + ((cb*4 + kc)*64 + lane)*8);
            bf16x8 bl = *(const bf16x8*)(Wlo + ((cb*4 + kc)*64 + lane)*8);
            acc[cb] = __builtin_amdgcn_mfma_f32_16x16x32_bf16(ahi, bh, acc[cb], 0, 0, 0);
            acc[cb] = __builtin_amdgcn_mfma_f32_16x16x32_bf16(alo, bh, acc[cb], 0, 0, 0);
            acc[cb] = __builtin_amdgcn_mfma_f32_16x16x32_bf16(ahi, bl, acc[cb], 0, 0, 0);
        }
    }
    float s[4];
    #pragma unroll
    for (int reg = 0; reg < 4; ++reg)
        s[reg] = SCALE ? rowscale[rbase + q*4 + reg] : 1.0f;
    #pragma unroll
    for (int cb = 0; cb < F/16; ++cb)
        #pragma unroll
        for (int reg = 0; reg < 4; ++reg)
            xw[(size_t)(rbase + q*4 + reg)*F + cb*16 + m] = (__bf16)(acc[cb][reg] * s[reg]);
}

// ---------- layer-2 MFMA GEMM, bf16 A direct, LDS-staged W ----------
template<int F>
__global__ __launch_bounds__(256) void gemm_mfma_bf16(const __bf16* __restrict__ X,
        __bf16* __restrict__ xw, int nchunks)
{
    __shared__ __bf16 Whi[(F/16)*4*64*8];
    __shared__ __bf16 Wlo[(F/16)*4*64*8];
    {
        const uint4* gh = (const uint4*)((F == 128) ? g_w1hi : g_w2hi);
        const uint4* gl = (const uint4*)((F == 128) ? g_w1lo : g_w2lo);
        uint4* lh = (uint4*)Whi;
        uint4* ll = (uint4*)Wlo;
        constexpr int NU4 = 16 * F;
        for (int i = threadIdx.x; i < NU4; i += 256) {
            lh[i] = gh[i];
            ll[i] = gl[i];
        }
    }
    __syncthreads();
    const int lane = threadIdx.x & 63;
    const int m = lane & 15, q = lane >> 4;
    int c = blockIdx.x*4 + (threadIdx.x >> 6);
    if (c >= nchunks) return;
    int rbase = c*16;
    const __bf16* xrow = X + (size_t)(rbase + m)*128;
    f32x4 acc[F/16];
    #pragma unroll
    for (int i = 0; i < F/16; ++i) acc[i] = (f32x4)0.f;
    #pragma unroll
    for (int kc = 0; kc < 4; ++kc) {
        int kb = kc*32 + q*8;
        bf16x8 a = *(const bf16x8*)(xrow + kb);
        #pragma unroll
        for (int cb = 0; cb < F/16; ++cb) {
            bf16x8 bh = *(const bf16x8*)(Whi + ((cb*4 + kc)*64 + lane)*8);
            bf16x8 bl = *(const bf16x8*)(Wlo + ((cb*4 + kc)*64 + lane)*8);
            acc[cb] = __builtin_amdgcn_mfma_f32_16x16x32_bf16(a, bh, acc[cb], 0, 0, 0);
            acc[cb] = __builtin_amdgcn_mfma_f32_16x16x32_bf16(a, bl, acc[cb], 0, 0, 0);
        }
    }
    #pragma unroll
    for (int cb = 0; cb < F/16; ++cb)
        #pragma unroll
        for (int reg = 0; reg < 4; ++reg)
            xw[(size_t)(rbase + q*4 + reg)*F + cb*16 + m] = (__bf16)acc[cb][reg];
}

// ---------- layer-1 aggregate: quarter-wave per node ----------
__global__ __launch_bounds__(256) void agg_csr128(const int* __restrict__ row_ptr,
        const int* __restrict__ csr, const uint4* __restrict__ xw,
        const float* __restrict__ nd, const float* __restrict__ ns,
        const float* __restrict__ b, __bf16* __restrict__ out, int n)
{
    int r = blockIdx.x * 16 + (threadIdx.x >> 4);
    if (r >= n) return;
    const int ql = threadIdx.x & 15;
    int beg = row_ptr[r], end = row_ptr[r + 1];
    float a[8];
    {
        uint4 u = xw[(size_t)r * 16 + ql];          // self-loop
        a[0]=blo(u.x); a[1]=bhi(u.x); a[2]=blo(u.y); a[3]=bhi(u.y);
        a[4]=blo(u.z); a[5]=bhi(u.z); a[6]=blo(u.w); a[7]=bhi(u.w);
    }
    int j = beg;
    for (; j + 4 <= end; j += 4) {                  // 4 gathers in flight per lane
        int s0 = csr[j], s1 = csr[j+1], s2 = csr[j+2], s3 = csr[j+3];
        uint4 u0 = xw[(size_t)s0 * 16 + ql];
        uint4 u1 = xw[(size_t)s1 * 16 + ql];
        uint4 u2 = xw[(size_t)s2 * 16 + ql];
        uint4 u3 = xw[(size_t)s3 * 16 + ql];
        a[0]+=blo(u0.x)+blo(u1.x)+blo(u2.x)+blo(u3.x); a[1]+=bhi(u0.x)+bhi(u1.x)+bhi(u2.x)+bhi(u3.x);
        a[2]+=blo(u0.y)+blo(u1.y)+blo(u2.y)+blo(u3.y); a[3]+=bhi(u0.y)+bhi(u1.y)+bhi(u2.y)+bhi(u3.y);
        a[4]+=blo(u0.z)+blo(u1.z)+blo(u2.z)+blo(u3.z); a[5]+=bhi(u0.z)+bhi(u1.z)+bhi(u2.z)+bhi(u3.z);
        a[6]+=blo(u0.w)+blo(u1.w)+blo(u2.w)+blo(u3.w); a[7]+=bhi(u0.w)+bhi(u1.w)+bhi(u2.w)+bhi(u3.w);
    }
    for (; j < end; ++j) {
        uint4 u0 = xw[(size_t)csr[j] * 16 + ql];
        a[0]+=blo(u0.x); a[1]+=bhi(u0.x); a[2]+=blo(u0.y); a[3]+=bhi(u0.y);
        a[4]+=blo(u0.z); a[5]+=bhi(u0.z); a[6]+=blo(u0.w); a[7]+=bhi(u0.w);
    }
    float ndr = nd[r], nsr = ns[r];
    float4 b0 = *(const float4*)(b + ql * 8);
    float4 b1 = *(const float4*)(b + ql * 8 + 4);
    uint4 pk;
    pk.x = packbf(fmaxf(a[0]*ndr + b0.x, 0.f) * nsr, fmaxf(a[1]*ndr + b0.y, 0.f) * nsr);
    pk.y = packbf(fmaxf(a[2]*ndr + b0.z, 0.f) * nsr, fmaxf(a[3]*ndr + b0.w, 0.f) * nsr);
    pk.z = packbf(fmaxf(a[4]*ndr + b1.x, 0.f) * nsr, fmaxf(a[5]*ndr + b1.y, 0.f) * nsr);
    pk.w = packbf(fmaxf(a[6]*ndr + b1.z, 0.f) * nsr, fmaxf(a[7]*ndr + b1.w, 0.f) * nsr);
    ((uint4*)(out + (size_t)r * 128))[ql] = pk;
}

// ---------- layer-2 aggregate: eighth-wave (8 lanes) per node, uint4 lanes ----------
__global__ __launch_bounds__(256) void agg_csr64(const int* __restrict__ row_ptr,
        const int* __restrict__ csr, const uint4* __restrict__ xw,
        const float* __restrict__ nd, const float* __restrict__ b,
        float* __restrict__ out, int n)
{
    int r = blockIdx.x * 32 + (threadIdx.x >> 3);
    if (r >= n) return;
    const int ql = threadIdx.x & 7;
    int beg = row_ptr[r], end = row_ptr[r + 1];
    float a[8];
    {
        uint4 u = xw[(size_t)r * 8 + ql];           // self-loop
        a[0]=blo(u.x); a[1]=bhi(u.x); a[2]=blo(u.y); a[3]=bhi(u.y);
        a[4]=blo(u.z); a[5]=bhi(u.z); a[6]=blo(u.w); a[7]=bhi(u.w);
    }
    int j = beg;
    for (; j + 4 <= end; j += 4) {
        int s0 = csr[j], s1 = csr[j+1], s2 = csr[j+2], s3 = csr[j+3];
        uint4 u0 = xw[(size_t)s0 * 8 + ql];
        uint4 u1 = xw[(size_t)s1 * 8 + ql];
        uint4 u2 = xw[(size_t)s2 * 8 + ql];
        uint4 u3 = xw[(size_t)s3 * 8 + ql];
        a[0]+=blo(u0.x)+blo(u1.x)+blo(u2.x)+blo(u3.x); a[1]+=bhi(u0.x)+bhi(u1.x)+bhi(u2.x)+bhi(u3.x);
        a[2]+=blo(u0.y)+blo(u1.y)+blo(u2.y)+blo(u3.y); a[3]+=bhi(u0.y)+bhi(u1.y)+bhi(u2.y)+bhi(u3.y);
        a[4]+=blo(u0.z)+blo(u1.z)+blo(u2.z)+blo(u3.z); a[5]+=bhi(u0.z)+bhi(u1.z)+bhi(u2.z)+bhi(u3.z);
        a[6]+=blo(u0.w)+blo(u1.w)+blo(u2.w)+blo(u3.w); a[7]+=bhi(u0.w)+bhi(u1.w)+bhi(u2.w)+bhi(u3.w);
    }
    for (; j < end; ++j) {
        uint4 u0 = xw[(size_t)csr[j] * 8 + ql];
        a[0]+=blo(u0.x); a[1]+=bhi(u0.x); a[2]+=blo(u0.y); a[3]+=bhi(u0.y);
        a[4]+=blo(u0.z); a[5]+=bhi(u0.z); a[6]+=blo(u0.w); a[7]+=bhi(u0.w);
    }
    float ndr = nd[r];
    float4 b0 = *(const float4*)(b + ql * 8);
    float4 b1 = *(const float4*)(b + ql * 8 + 4);
    float4 o0, o1;
    o0.x = a[0]*ndr + b0.x;
    o0.y = a[1]*ndr + b0.y;
    o0.z = a[2]*ndr + b0.z;
    o0.w = a[3]*ndr + b0.w;
    o1.x = a[4]*ndr + b1.x;
    o1.y = a[5]*ndr + b1.y;
    o1.z = a[6]*ndr + b1.z;
    o1.w = a[7]*ndr + b1.w;
    float* op = out + (size_t)r * 64 + ql * 8;
    *(float4*)op = o0;
    *(float4*)(op + 4) = o1;
}

extern "C" void kernel_launch(void* const* d_in, const int* in_sizes, int n_in,
                              void* d_out, int out_size, void* d_ws, size_t ws_size,
                              hipStream_t stream)
{
    const float* x  = (const float*)d_in[0];   // [N,128] f32
    const int* src  = (const int*)d_in[1];     // [E]
    const int* dst  = (const int*)d_in[2];     // [E]
    const float* W1 = (const float*)d_in[3];   // [128,128] f32
    const float* b1 = (const float*)d_in[4];   // [128] f32
    const float* W2 = (const float*)d_in[5];   // [128,64] f32
    const float* b2 = (const float*)d_in[6];   // [64] f32
    float* out = (float*)d_out;                // [N,64] f32

    const int n = NN, e = NE;
    const int nchunks = n / 16;                // 6250, exact
    const int gemm_grid = (nchunks + 3) / 4;   // 1563

    // workspace layout
    char* p = (char*)d_ws;
    float* ns      = (float*)p; p += (size_t)n * 4;
    float* nd      = (float*)p; p += (size_t)n * 4;
    int*   row_ptr = (int*)p;   p += (size_t)(n + 1) * 4;
    int*   cd      = (int*)p;   p += (size_t)NBUCK * 4;     // cd,cs adjacent: zeroed together
    int*   cs      = (int*)p;   p += (size_t)NBUCK * 4;
    int*   offd    = (int*)p;   p += (size_t)(NBUCK + 1) * 4;
    int*   offs    = (int*)p;   p += (size_t)(NBUCK + 1) * 4;
    int*   curd    = (int*)p;   p += (size_t)NBUCK * 4;
    int*   curs    = (int*)p;   p += (size_t)NBUCK * 4;
    int*   csr     = (int*)p;   p += (size_t)e * 4;
    p = (char*)(((uintptr_t)p + 255) & ~(uintptr_t)255);
    __bf16* bufA   = (__bf16*)p; p += (size_t)128 * n * 2;  // xw1 bf16, then xw2 bf16
    p = (char*)(((uintptr_t)p + 255) & ~(uintptr_t)255);
    __bf16* bufB   = (__bf16*)p;                             // h bf16 [N,128]
    uint*  pairs   = (uint*)bufB;                            // build-phase only
    int*   bsrc    = (int*)bufA;                             // build-phase only

    prep_w<<<16, 256, 0, stream>>>(W1, W2, cd);
    coarse_hist<<<256, 256, 0, stream>>>((const int4*)src, (const int4*)dst, cd, cs, e / 4);
    scan_coarse<<<1, 512, 0, stream>>>(cd, cs, offd, offs, curd, curs, row_ptr, n, e);
    part_both<<<NPART, 1024, 0, stream>>>(src, dst, curd, curs, pairs, bsrc, e);
    fine_both<<<NBUCK, 256, 0, stream>>>(offd, pairs, offs, bsrc, row_ptr, nd, ns, csr, n);

    // layer 1: xw1 = bf16((x @ W1) * ns) ; h = bf16(relu((xw1[r]+sum nbr)*nd + b1) * ns)
    gemm_mfma<128, true><<<gemm_grid, 256, 0, stream>>>(x, ns, bufA, nchunks);
    agg_csr128<<<(n + 15) / 16, 256, 0, stream>>>(row_ptr, csr, (const uint4*)bufA, nd, ns, b1, bufB, n);

    // layer 2: xw2 = bf16(h @ W2) ; out = (xw2[r]+sum nbr)*nd + b2
    gemm_mfma_bf16<64><<<gemm_grid, 256, 0, stream>>>(bufB, bufA, nchunks);
    agg_csr64<<<(n + 31) / 32, 256, 0, stream>>>(row_ptr, csr, (const uint4*)bufA, nd, b2, out, n);
}

// Round 10
// 290.707 us; speedup vs baseline: 1.0989x; 1.0265x over previous
//
#include <hip/hip_runtime.h>
#include <stdint.h>

#define NN 100000
#define NE 1600000
#define NBUCK 391            // ceil(NN/256)
#define CHUNK 16000          // big runs/bucket/chunk: single-XCD-owned scatter lines
#define NPART (NE / CHUNK)   // 100, exact

typedef __attribute__((ext_vector_type(8))) __bf16 bf16x8;
typedef __attribute__((ext_vector_type(4))) float  f32x4;
typedef unsigned int uint;

static __device__ __forceinline__ float blo(uint u) {
    union { uint i; float f; } v; v.i = u << 16; return v.f;
}
static __device__ __forceinline__ float bhi(uint u) {
    union { uint i; float f; } v; v.i = u & 0xffff0000u; return v.f;
}
static __device__ __forceinline__ uint packbf(float a, float b) {
    union { __bf16 h[2]; uint u; } v;
    v.h[0] = (__bf16)a; v.h[1] = (__bf16)b;
    return v.u;
}

// Preformatted W in the exact LDS fragment layout (hi/lo bf16 split).
__device__ __align__(16) __bf16 g_w1hi[16384];
__device__ __align__(16) __bf16 g_w1lo[16384];
__device__ __align__(16) __bf16 g_w2hi[8192];
__device__ __align__(16) __bf16 g_w2lo[8192];

// ---------- prep_w fused with counter zeroing ----------
__global__ __launch_bounds__(256) void prep_w(const float* __restrict__ W1,
        const float* __restrict__ W2, int* __restrict__ cdcs)
{
    int gid = blockIdx.x * 256 + threadIdx.x;
    if (gid >= 3072) {
        int z = gid - 3072;
        if (z < 2 * NBUCK) cdcs[z] = 0;
        return;
    }
    const float* W; __bf16* hi; __bf16* lo; int F; int idx;
    if (gid < 2048)      { W = W1; hi = g_w1hi; lo = g_w1lo; F = 128; idx = gid; }
    else                 { W = W2; hi = g_w2hi; lo = g_w2lo; F = 64;  idx = gid - 2048; }
    int cb = idx >> 8;
    int kc = (idx >> 6) & 3;
    int ln = idx & 63;
    int col = cb*16 + (ln & 15);
    int kb  = kc*32 + (ln >> 4)*8;
    bf16x8 vh, vl;
    #pragma unroll
    for (int j = 0; j < 8; ++j) {
        float f = W[(size_t)(kb + j)*F + col];
        __bf16 h = (__bf16)f;
        vh[j] = h;
        vl[j] = (__bf16)(f - (float)h);
    }
    *(bf16x8*)(hi + idx*8) = vh;
    *(bf16x8*)(lo + idx*8) = vl;
}

// 100 blocks x 1024 threads, 4-way replicated LDS histograms (same treatment
// that fixed part_both's LDS-atomic serialization in R7).
__global__ __launch_bounds__(1024) void coarse_hist(const int4* __restrict__ src4,
        const int4* __restrict__ dst4, int* __restrict__ cd, int* __restrict__ cs, int e4)
{
    __shared__ int hd[4][NBUCK], hs[4][NBUCK];
    for (int t = threadIdx.x; t < NBUCK; t += 1024) {
        hd[0][t] = 0; hd[1][t] = 0; hd[2][t] = 0; hd[3][t] = 0;
        hs[0][t] = 0; hs[1][t] = 0; hs[2][t] = 0; hs[3][t] = 0;
    }
    __syncthreads();
    const int c = (threadIdx.x >> 6) & 3;
    int beg4 = blockIdx.x * (CHUNK / 4);
    int end4 = beg4 + (CHUNK / 4); if (end4 > e4) end4 = e4;
    for (int i = beg4 + threadIdx.x; i < end4; i += 1024) {
        int4 d = dst4[i], s = src4[i];
        atomicAdd(&hd[c][d.x >> 8], 1); atomicAdd(&hd[c][d.y >> 8], 1);
        atomicAdd(&hd[c][d.z >> 8], 1); atomicAdd(&hd[c][d.w >> 8], 1);
        atomicAdd(&hs[c][s.x >> 8], 1); atomicAdd(&hs[c][s.y >> 8], 1);
        atomicAdd(&hs[c][s.z >> 8], 1); atomicAdd(&hs[c][s.w >> 8], 1);
    }
    __syncthreads();
    for (int t = threadIdx.x; t < NBUCK; t += 1024) {
        int vd = hd[0][t] + hd[1][t] + hd[2][t] + hd[3][t];
        int vs = hs[0][t] + hs[1][t] + hs[2][t] + hs[3][t];
        if (vd) atomicAdd(&cd[t], vd);
        if (vs) atomicAdd(&cs[t], vs);
    }
}

__global__ __launch_bounds__(512) void scan_coarse(const int* __restrict__ cd,
        const int* __restrict__ cs, int* __restrict__ offd, int* __restrict__ offs,
        int* __restrict__ curd, int* __restrict__ curs, int* __restrict__ row_ptr,
        int n, int e)
{
    __shared__ int sh[512];
    int t = threadIdx.x;
    int v = (t < NBUCK) ? cd[t] : 0;
    sh[t] = v;
    __syncthreads();
    for (int o = 1; o < 512; o <<= 1) {
        int tv = (t >= o) ? sh[t - o] : 0;
        __syncthreads();
        sh[t] += tv;
        __syncthreads();
    }
    if (t < NBUCK) { int ex = sh[t] - v; offd[t] = ex; curd[t] = ex; }
    if (t == 0) { offd[NBUCK] = e; row_ptr[n] = e; }
    __syncthreads();
    v = (t < NBUCK) ? cs[t] : 0;
    sh[t] = v;
    __syncthreads();
    for (int o = 1; o < 512; o <<= 1) {
        int tv = (t >= o) ? sh[t - o] : 0;
        __syncthreads();
        sh[t] += tv;
        __syncthreads();
    }
    if (t < NBUCK) { int ex = sh[t] - v; offs[t] = ex; curs[t] = ex; }
    if (t == 0) offs[NBUCK] = e;
}

// partition edges by dst>>8 (packed 4B pairs) AND src values by src>>8 (bsrc).
// CHUNK=16000, block=1024: per-bucket runs ~160B so pairs/bsrc lines are
// single-XCD-owned (write amp ~5.5x -> ~1.4x). 4-way hist copies cut LDS
// atomic serialization in the counting phase.
__global__ __launch_bounds__(1024) void part_both(const int* __restrict__ src,
        const int* __restrict__ dst, int* __restrict__ curd, int* __restrict__ curs,
        uint* __restrict__ pairs, int* __restrict__ bsrc, int e)
{
    __shared__ int hd[4][NBUCK], hs[4][NBUCK];
    __shared__ int based[NBUCK], bases[NBUCK];
    int beg = blockIdx.x * CHUNK;
    int end = beg + CHUNK; if (end > e) end = e;
    for (int t = threadIdx.x; t < NBUCK; t += 1024) {
        hd[0][t] = 0; hd[1][t] = 0; hd[2][t] = 0; hd[3][t] = 0;
        hs[0][t] = 0; hs[1][t] = 0; hs[2][t] = 0; hs[3][t] = 0;
    }
    __syncthreads();
    const int c = (threadIdx.x >> 6) & 3;
    for (int i = beg + threadIdx.x * 4; i + 4 <= end; i += 4096) {
        int4 d = *(const int4*)(dst + i);
        int4 s = *(const int4*)(src + i);
        atomicAdd(&hd[c][d.x >> 8], 1); atomicAdd(&hd[c][d.y >> 8], 1);
        atomicAdd(&hd[c][d.z >> 8], 1); atomicAdd(&hd[c][d.w >> 8], 1);
        atomicAdd(&hs[c][s.x >> 8], 1); atomicAdd(&hs[c][s.y >> 8], 1);
        atomicAdd(&hs[c][s.z >> 8], 1); atomicAdd(&hs[c][s.w >> 8], 1);
    }
    __syncthreads();
    for (int t = threadIdx.x; t < NBUCK; t += 1024) {
        int vd = hd[0][t] + hd[1][t] + hd[2][t] + hd[3][t];
        int vs = hs[0][t] + hs[1][t] + hs[2][t] + hs[3][t];
        based[t] = vd ? atomicAdd(&curd[t], vd) : 0;
        bases[t] = vs ? atomicAdd(&curs[t], vs) : 0;
    }
    __syncthreads();
    for (int i = beg + threadIdx.x; i < end; i += 1024) {
        int s = src[i], d = dst[i];
        int pd = atomicAdd(&based[d >> 8], 1);     // LDS atomic
        pairs[pd] = ((uint)(d & 255) << 24) | (uint)s;
        int ps = atomicAdd(&bases[s >> 8], 1);     // LDS atomic
        bsrc[ps] = s;
    }
}

__global__ __launch_bounds__(256) void fine_both(const int* __restrict__ offd,
        const uint* __restrict__ pairs, const int* __restrict__ offs,
        const int* __restrict__ bsrc, int* __restrict__ row_ptr,
        float* __restrict__ nd, float* __restrict__ ns, int* __restrict__ csr, int n)
{
    __shared__ int h[256], sh[256], cur[256];
    int b = blockIdx.x;
    int t = threadIdx.x;
    int node = (b << 8) + t;
    // ---- dst phase ----
    int beg = offd[b], end = offd[b + 1];
    h[t] = 0;
    __syncthreads();
    for (int i = beg + t; i < end; i += 256)
        atomicAdd(&h[pairs[i] >> 24], 1);
    __syncthreads();
    int v = h[t];
    sh[t] = v;
    __syncthreads();
    for (int o = 1; o < 256; o <<= 1) {
        int tv = (t >= o) ? sh[t - o] : 0;
        __syncthreads();
        sh[t] += tv;
        __syncthreads();
    }
    int ex = sh[t] - v;
    if (node < n) {
        row_ptr[node] = beg + ex;
        nd[node] = rsqrtf((float)v + 1.0f);        // +1 self-loop
    }
    cur[t] = beg + ex;
    __syncthreads();
    for (int i = beg + t; i < end; i += 256) {
        uint pr = pairs[i];
        int pos = atomicAdd(&cur[pr >> 24], 1);    // LDS atomic
        csr[pos] = (int)(pr & 0x00FFFFFFu);
    }
    // ---- src phase ----
    h[t] = 0;
    __syncthreads();
    int sbeg = offs[b], send = offs[b + 1];
    for (int i = sbeg + t; i < send; i += 256)
        atomicAdd(&h[bsrc[i] & 255], 1);
    __syncthreads();
    if (node < n) ns[node] = rsqrtf((float)h[t] + 1.0f);
}

// ---------- layer-1 MFMA GEMM, f32 A via split-bf16, LDS-staged W ----------
template<int F, bool SCALE>
__global__ __launch_bounds__(256) void gemm_mfma(const float* __restrict__ X,
        const float* __restrict__ rowscale, __bf16* __restrict__ xw, int nchunks)
{
    __shared__ __bf16 Whi[(F/16)*4*64*8];
    __shared__ __bf16 Wlo[(F/16)*4*64*8];
    {
        const uint4* gh = (const uint4*)((F == 128) ? g_w1hi : g_w2hi);
        const uint4* gl = (const uint4*)((F == 128) ? g_w1lo : g_w2lo);
        uint4* lh = (uint4*)Whi;
        uint4* ll = (uint4*)Wlo;
        constexpr int NU4 = 16 * F;
        for (int i = threadIdx.x; i < NU4; i += 256) {
            lh[i] = gh[i];
            ll[i] = gl[i];
        }
    }
    __syncthreads();
    const int lane = threadIdx.x & 63;
    const int m = lane & 15, q = lane >> 4;
    int c = blockIdx.x*4 + (threadIdx.x >> 6);
    if (c >= nchunks) return;
    int rbase = c*16;
    const float* xrow = X + (size_t)(rbase + m)*128;
    f32x4 acc[F/16];
    #pragma unroll
    for (int i = 0; i < F/16; ++i) acc[i] = (f32x4)0.f;
    #pragma unroll
    for (int kc = 0; kc < 4; ++kc) {
        int kb = kc*32 + q*8;
        float4 v0 = *(const float4*)(xrow + kb);
        float4 v1 = *(const float4*)(xrow + kb + 4);
        float xf[8] = {v0.x, v0.y, v0.z, v0.w, v1.x, v1.y, v1.z, v1.w};
        bf16x8 ahi, alo;
        #pragma unroll
        for (int j = 0; j < 8; ++j) {
            __bf16 h = (__bf16)xf[j];
            ahi[j] = h;
            alo[j] = (__bf16)(xf[j] - (float)h);
        }
        #pragma unroll
        for (int cb = 0; cb < F/16; ++cb) {
            bf16x8 bh = *(const bf16x8*)(Whi + ((cb*4 + kc)*64 + lane)*8);
            bf16x8 bl = *(const bf16x8*)(Wlo + ((cb*4 + kc)*64 + lane)*8);
            acc[cb] = __builtin_amdgcn_mfma_f32_16x16x32_bf16(ahi, bh, acc[cb], 0, 0, 0);
            acc[cb] = __builtin_amdgcn_mfma_f32_16x16x32_bf16(alo, bh, acc[cb], 0, 0, 0);
            acc[cb] = __builtin_amdgcn_mfma_f32_16x16x32_bf16(ahi, bl, acc[cb], 0, 0, 0);
        }
    }
    float s[4];
    #pragma unroll
    for (int reg = 0; reg < 4; ++reg)
        s[reg] = SCALE ? rowscale[rbase + q*4 + reg] : 1.0f;
    #pragma unroll
    for (int cb = 0; cb < F/16; ++cb)
        #pragma unroll
        for (int reg = 0; reg < 4; ++reg)
            xw[(size_t)(rbase + q*4 + reg)*F + cb*16 + m] = (__bf16)(acc[cb][reg] * s[reg]);
}

// ---------- layer-2 MFMA GEMM, bf16 A direct, LDS-staged W ----------
template<int F>
__global__ __launch_bounds__(256) void gemm_mfma_bf16(const __bf16* __restrict__ X,
        __bf16* __restrict__ xw, int nchunks)
{
    __shared__ __bf16 Whi[(F/16)*4*64*8];
    __shared__ __bf16 Wlo[(F/16)*4*64*8];
    {
        const uint4* gh = (const uint4*)((F == 128) ? g_w1hi : g_w2hi);
        const uint4* gl = (const uint4*)((F == 128) ? g_w1lo : g_w2lo);
        uint4* lh = (uint4*)Whi;
        uint4* ll = (uint4*)Wlo;
        constexpr int NU4 = 16 * F;
        for (int i = threadIdx.x; i < NU4; i += 256) {
            lh[i] = gh[i];
            ll[i] = gl[i];
        }
    }
    __syncthreads();
    const int lane = threadIdx.x & 63;
    const int m = lane & 15, q = lane >> 4;
    int c = blockIdx.x*4 + (threadIdx.x >> 6);
    if (c >= nchunks) return;
    int rbase = c*16;
    const __bf16* xrow = X + (size_t)(rbase + m)*128;
    f32x4 acc[F/16];
    #pragma unroll
    for (int i = 0; i < F/16; ++i) acc[i] = (f32x4)0.f;
    #pragma unroll
    for (int kc = 0; kc < 4; ++kc) {
        int kb = kc*32 + q*8;
        bf16x8 a = *(const bf16x8*)(xrow + kb);
        #pragma unroll
        for (int cb = 0; cb < F/16; ++cb) {
            bf16x8 bh = *(const bf16x8*)(Whi + ((cb*4 + kc)*64 + lane)*8);
            bf16x8 bl = *(const bf16x8*)(Wlo + ((cb*4 + kc)*64 + lane)*8);
            acc[cb] = __builtin_amdgcn_mfma_f32_16x16x32_bf16(a, bh, acc[cb], 0, 0, 0);
            acc[cb] = __builtin_amdgcn_mfma_f32_16x16x32_bf16(a, bl, acc[cb], 0, 0, 0);
        }
    }
    #pragma unroll
    for (int cb = 0; cb < F/16; ++cb)
        #pragma unroll
        for (int reg = 0; reg < 4; ++reg)
            xw[(size_t)(rbase + q*4 + reg)*F + cb*16 + m] = (__bf16)acc[cb][reg];
}

// ---------- layer-1 aggregate: quarter-wave per node ----------
__global__ __launch_bounds__(256) void agg_csr128(const int* __restrict__ row_ptr,
        const int* __restrict__ csr, const uint4* __restrict__ xw,
        const float* __restrict__ nd, const float* __restrict__ ns,
        const float* __restrict__ b, __bf16* __restrict__ out, int n)
{
    int r = blockIdx.x * 16 + (threadIdx.x >> 4);
    if (r >= n) return;
    const int ql = threadIdx.x & 15;
    int beg = row_ptr[r], end = row_ptr[r + 1];
    float a[8];
    {
        uint4 u = xw[(size_t)r * 16 + ql];          // self-loop
        a[0]=blo(u.x); a[1]=bhi(u.x); a[2]=blo(u.y); a[3]=bhi(u.y);
        a[4]=blo(u.z); a[5]=bhi(u.z); a[6]=blo(u.w); a[7]=bhi(u.w);
    }
    int j = beg;
    for (; j + 4 <= end; j += 4) {                  // 4 gathers in flight per lane
        int s0 = csr[j], s1 = csr[j+1], s2 = csr[j+2], s3 = csr[j+3];
        uint4 u0 = xw[(size_t)s0 * 16 + ql];
        uint4 u1 = xw[(size_t)s1 * 16 + ql];
        uint4 u2 = xw[(size_t)s2 * 16 + ql];
        uint4 u3 = xw[(size_t)s3 * 16 + ql];
        a[0]+=blo(u0.x)+blo(u1.x)+blo(u2.x)+blo(u3.x); a[1]+=bhi(u0.x)+bhi(u1.x)+bhi(u2.x)+bhi(u3.x);
        a[2]+=blo(u0.y)+blo(u1.y)+blo(u2.y)+blo(u3.y); a[3]+=bhi(u0.y)+bhi(u1.y)+bhi(u2.y)+bhi(u3.y);
        a[4]+=blo(u0.z)+blo(u1.z)+blo(u2.z)+blo(u3.z); a[5]+=bhi(u0.z)+bhi(u1.z)+bhi(u2.z)+bhi(u3.z);
        a[6]+=blo(u0.w)+blo(u1.w)+blo(u2.w)+blo(u3.w); a[7]+=bhi(u0.w)+bhi(u1.w)+bhi(u2.w)+bhi(u3.w);
    }
    for (; j < end; ++j) {
        uint4 u0 = xw[(size_t)csr[j] * 16 + ql];
        a[0]+=blo(u0.x); a[1]+=bhi(u0.x); a[2]+=blo(u0.y); a[3]+=bhi(u0.y);
        a[4]+=blo(u0.z); a[5]+=bhi(u0.z); a[6]+=blo(u0.w); a[7]+=bhi(u0.w);
    }
    float ndr = nd[r], nsr = ns[r];
    float4 b0 = *(const float4*)(b + ql * 8);
    float4 b1 = *(const float4*)(b + ql * 8 + 4);
    uint4 pk;
    pk.x = packbf(fmaxf(a[0]*ndr + b0.x, 0.f) * nsr, fmaxf(a[1]*ndr + b0.y, 0.f) * nsr);
    pk.y = packbf(fmaxf(a[2]*ndr + b0.z, 0.f) * nsr, fmaxf(a[3]*ndr + b0.w, 0.f) * nsr);
    pk.z = packbf(fmaxf(a[4]*ndr + b1.x, 0.f) * nsr, fmaxf(a[5]*ndr + b1.y, 0.f) * nsr);
    pk.w = packbf(fmaxf(a[6]*ndr + b1.z, 0.f) * nsr, fmaxf(a[7]*ndr + b1.w, 0.f) * nsr);
    ((uint4*)(out + (size_t)r * 128))[ql] = pk;
}

// ---------- layer-2 aggregate: eighth-wave (8 lanes) per node, uint4 lanes ----------
__global__ __launch_bounds__(256) void agg_csr64(const int* __restrict__ row_ptr,
        const int* __restrict__ csr, const uint4* __restrict__ xw,
        const float* __restrict__ nd, const float* __restrict__ b,
        float* __restrict__ out, int n)
{
    int r = blockIdx.x * 32 + (threadIdx.x >> 3);
    if (r >= n) return;
    const int ql = threadIdx.x & 7;
    int beg = row_ptr[r], end = row_ptr[r + 1];
    float a[8];
    {
        uint4 u = xw[(size_t)r * 8 + ql];           // self-loop
        a[0]=blo(u.x); a[1]=bhi(u.x); a[2]=blo(u.y); a[3]=bhi(u.y);
        a[4]=blo(u.z); a[5]=bhi(u.z); a[6]=blo(u.w); a[7]=bhi(u.w);
    }
    int j = beg;
    for (; j + 4 <= end; j += 4) {
        int s0 = csr[j], s1 = csr[j+1], s2 = csr[j+2], s3 = csr[j+3];
        uint4 u0 = xw[(size_t)s0 * 8 + ql];
        uint4 u1 = xw[(size_t)s1 * 8 + ql];
        uint4 u2 = xw[(size_t)s2 * 8 + ql];
        uint4 u3 = xw[(size_t)s3 * 8 + ql];
        a[0]+=blo(u0.x)+blo(u1.x)+blo(u2.x)+blo(u3.x); a[1]+=bhi(u0.x)+bhi(u1.x)+bhi(u2.x)+bhi(u3.x);
        a[2]+=blo(u0.y)+blo(u1.y)+blo(u2.y)+blo(u3.y); a[3]+=bhi(u0.y)+bhi(u1.y)+bhi(u2.y)+bhi(u3.y);
        a[4]+=blo(u0.z)+blo(u1.z)+blo(u2.z)+blo(u3.z); a[5]+=bhi(u0.z)+bhi(u1.z)+bhi(u2.z)+bhi(u3.z);
        a[6]+=blo(u0.w)+blo(u1.w)+blo(u2.w)+blo(u3.w); a[7]+=bhi(u0.w)+bhi(u1.w)+bhi(u2.w)+bhi(u3.w);
    }
    for (; j < end; ++j) {
        uint4 u0 = xw[(size_t)csr[j] * 8 + ql];
        a[0]+=blo(u0.x); a[1]+=bhi(u0.x); a[2]+=blo(u0.y); a[3]+=bhi(u0.y);
        a[4]+=blo(u0.z); a[5]+=bhi(u0.z); a[6]+=blo(u0.w); a[7]+=bhi(u0.w);
    }
    float ndr = nd[r];
    float4 b0 = *(const float4*)(b + ql * 8);
    float4 b1 = *(const float4*)(b + ql * 8 + 4);
    float4 o0, o1;
    o0.x = a[0]*ndr + b0.x;
    o0.y = a[1]*ndr + b0.y;
    o0.z = a[2]*ndr + b0.z;
    o0.w = a[3]*ndr + b0.w;
    o1.x = a[4]*ndr + b1.x;
    o1.y = a[5]*ndr + b1.y;
    o1.z = a[6]*ndr + b1.z;
    o1.w = a[7]*ndr + b1.w;
    float* op = out + (size_t)r * 64 + ql * 8;
    *(float4*)op = o0;
    *(float4*)(op + 4) = o1;
}

extern "C" void kernel_launch(void* const* d_in, const int* in_sizes, int n_in,
                              void* d_out, int out_size, void* d_ws, size_t ws_size,
                              hipStream_t stream)
{
    const float* x  = (const float*)d_in[0];   // [N,128] f32
    const int* src  = (const int*)d_in[1];     // [E]
    const int* dst  = (const int*)d_in[2];     // [E]
    const float* W1 = (const float*)d_in[3];   // [128,128] f32
    const float* b1 = (const float*)d_in[4];   // [128] f32
    const float* W2 = (const float*)d_in[5];   // [128,64] f32
    const float* b2 = (const float*)d_in[6];   // [64] f32
    float* out = (float*)d_out;                // [N,64] f32

    const int n = NN, e = NE;
    const int nchunks = n / 16;                // 6250, exact
    const int gemm_grid = (nchunks + 3) / 4;   // 1563

    // workspace layout
    char* p = (char*)d_ws;
    float* ns      = (float*)p; p += (size_t)n * 4;
    float* nd      = (float*)p; p += (size_t)n * 4;
    int*   row_ptr = (int*)p;   p += (size_t)(n + 1) * 4;
    int*   cd      = (int*)p;   p += (size_t)NBUCK * 4;     // cd,cs adjacent: zeroed together
    int*   cs      = (int*)p;   p += (size_t)NBUCK * 4;
    int*   offd    = (int*)p;   p += (size_t)(NBUCK + 1) * 4;
    int*   offs    = (int*)p;   p += (size_t)(NBUCK + 1) * 4;
    int*   curd    = (int*)p;   p += (size_t)NBUCK * 4;
    int*   curs    = (int*)p;   p += (size_t)NBUCK * 4;
    int*   csr     = (int*)p;   p += (size_t)e * 4;
    p = (char*)(((uintptr_t)p + 255) & ~(uintptr_t)255);
    __bf16* bufA   = (__bf16*)p; p += (size_t)128 * n * 2;  // xw1 bf16, then xw2 bf16
    p = (char*)(((uintptr_t)p + 255) & ~(uintptr_t)255);
    __bf16* bufB   = (__bf16*)p;                             // h bf16 [N,128]
    uint*  pairs   = (uint*)bufB;                            // build-phase only
    int*   bsrc    = (int*)bufA;                             // build-phase only

    prep_w<<<16, 256, 0, stream>>>(W1, W2, cd);
    coarse_hist<<<NPART, 1024, 0, stream>>>((const int4*)src, (const int4*)dst, cd, cs, e / 4);
    scan_coarse<<<1, 512, 0, stream>>>(cd, cs, offd, offs, curd, curs, row_ptr, n, e);
    part_both<<<NPART, 1024, 0, stream>>>(src, dst, curd, curs, pairs, bsrc, e);
    fine_both<<<NBUCK, 256, 0, stream>>>(offd, pairs, offs, bsrc, row_ptr, nd, ns, csr, n);

    // layer 1: xw1 = bf16((x @ W1) * ns) ; h = bf16(relu((xw1[r]+sum nbr)*nd + b1) * ns)
    gemm_mfma<128, true><<<gemm_grid, 256, 0, stream>>>(x, ns, bufA, nchunks);
    agg_csr128<<<(n + 15) / 16, 256, 0, stream>>>(row_ptr, csr, (const uint4*)bufA, nd, ns, b1, bufB, n);

    // layer 2: xw2 = bf16(h @ W2) ; out = (xw2[r]+sum nbr)*nd + b2
    gemm_mfma_bf16<64><<<gemm_grid, 256, 0, stream>>>(bufB, bufA, nchunks);
    agg_csr64<<<(n + 31) / 32, 256, 0, stream>>>(row_ptr, csr, (const uint4*)bufA, nd, b2, out, n);
}